// Round 10
// baseline (2697.922 us; speedup 1.0000x reference)
//
#include <hip/hip_runtime.h>
#include <math.h>

#define NL 576   // H*W = 24*24
#define NCH 64   // DIM

#define DOT4(acc, xv, w0, w1, w2, w3)                               \
    acc.x += xv.x*w0.x + xv.y*w1.x + xv.z*w2.x + xv.w*w3.x;         \
    acc.y += xv.x*w0.y + xv.y*w1.y + xv.z*w2.y + xv.w*w3.y;         \
    acc.z += xv.x*w0.z + xv.y*w1.z + xv.z*w2.z + xv.w*w3.z;         \
    acc.w += xv.x*w0.w + xv.y*w1.w + xv.z*w2.w + xv.w*w3.w;

// ---------------------------------------------------------------------------
// KA: LN1 + QKV projection + windowed attention.
// One block per (b, u) = one row of 8 windows (72 tokens).
// o1 layout: [B][64 win][9 tok][64 ch], ch = head*16 + d.
// ---------------------------------------------------------------------------
__global__ __launch_bounds__(512) void ka_kernel(
    const float* __restrict__ x, const float* __restrict__ qkv_w,
    const float* __restrict__ qkv_b, const float* __restrict__ rel_table,
    const float* __restrict__ n1g, const float* __restrict__ n1b,
    float* __restrict__ o1)
{
    const int u = blockIdx.x;
    const int b = blockIdx.y;
    const int tid = threadIdx.x;

    __shared__ __align__(16) float xt[72][68];      // normalized tokens [p][c]
    __shared__ __align__(16) float qwT[64][200];    // qkv_w transposed [c][j]
    __shared__ __align__(16) float qkv_s[72][200];  // qkv output [p][j]
    __shared__ __align__(16) float qb_s[192];
    __shared__ float mean_s[72], rstd_s[72];

    const float* xb = x + (size_t)b * NCH * NL;

    // load x tile (coalesced: 72 contiguous floats per channel-row)
    for (int idx = tid; idx < 64 * 72; idx += 512) {
        int c = idx / 72, r = idx % 72;
        int hi = r / 24, wc = r % 24;
        int p = (wc / 3) * 9 + hi * 3 + (wc % 3);   // win*9 + tok
        xt[p][c] = xb[c * NL + (u * 3 + hi) * 24 + wc];
    }
    // stage qkv_w transposed (global read coalesced)
    for (int idx = tid; idx < 12288; idx += 512) {
        int j = idx >> 6, c = idx & 63;
        qwT[c][j] = qkv_w[idx];
    }
    if (tid < 192) qb_s[tid] = qkv_b[tid];
    __syncthreads();

    // LN stats: 4 lanes per token, shfl-xor tree (all groups within a wave)
    if (tid < 288) {
        const int p = tid >> 2, q = tid & 3;
        float s = 0.f, sq = 0.f;
        #pragma unroll
        for (int c = 0; c < 16; c += 4) {
            float4 v = *(const float4*)&xt[p][q * 16 + c];
            s  += v.x + v.y + v.z + v.w;
            sq += v.x*v.x + v.y*v.y + v.z*v.z + v.w*v.w;
        }
        s += __shfl_xor(s, 1); sq += __shfl_xor(sq, 1);
        s += __shfl_xor(s, 2); sq += __shfl_xor(sq, 2);
        if (q == 0) {
            float m = s * 0.015625f;
            float var = sq * 0.015625f - m * m;
            mean_s[p] = m;
            rstd_s[p] = rsqrtf(var + 1e-5f);
        }
    }
    __syncthreads();
    // normalize in place
    for (int idx = tid; idx < 72 * 64; idx += 512) {
        int p = idx >> 6, c = idx & 63;
        xt[p][c] = (xt[p][c] - mean_s[p]) * rstd_s[p] * n1g[c] + n1b[c];
    }
    __syncthreads();

    // QKV GEMM: 4p x 4j register tiles. 18*48 = 864 tiles.
    for (int o = tid; o < 864; o += 512) {
        const int p0 = (o / 48) * 4;
        const int j0 = (o % 48) * 4;
        float4 a0 = *(const float4*)&qb_s[j0];
        float4 a1 = a0, a2 = a0, a3 = a0;
        for (int c = 0; c < 64; c += 4) {
            float4 x0 = *(const float4*)&xt[p0 + 0][c];
            float4 x1 = *(const float4*)&xt[p0 + 1][c];
            float4 x2 = *(const float4*)&xt[p0 + 2][c];
            float4 x3 = *(const float4*)&xt[p0 + 3][c];
            float4 w0 = *(const float4*)&qwT[c + 0][j0];
            float4 w1 = *(const float4*)&qwT[c + 1][j0];
            float4 w2 = *(const float4*)&qwT[c + 2][j0];
            float4 w3 = *(const float4*)&qwT[c + 3][j0];
            DOT4(a0, x0, w0, w1, w2, w3)
            DOT4(a1, x1, w0, w1, w2, w3)
            DOT4(a2, x2, w0, w1, w2, w3)
            DOT4(a3, x3, w0, w1, w2, w3)
        }
        *(float4*)&qkv_s[p0 + 0][j0] = a0;
        *(float4*)&qkv_s[p0 + 1][j0] = a1;
        *(float4*)&qkv_s[p0 + 2][j0] = a2;
        *(float4*)&qkv_s[p0 + 3][j0] = a3;
    }
    __syncthreads();

    // attention: one thread per (win, head, q-token) = 288 threads.
    // channel split: qkv channel = d*4 + head; q at j, k at 64+j, v at 128+j.
    if (tid < 288) {
        const int win = tid / 36;
        const int rr = tid % 36;
        const int head = rr / 9, qtok = rr % 9;
        const int qi = qtok / 3, qj = qtok % 3;
        float sc[9];
        float mx = -1e30f;
        for (int kt = 0; kt < 9; ++kt) {
            float dot = 0.f;
            for (int d = 0; d < 16; ++d)
                dot += qkv_s[win * 9 + qtok][d * 4 + head] *
                       qkv_s[win * 9 + kt][64 + d * 4 + head];
            int di = qi - kt / 3 + 2, dj = qj - kt % 3 + 2;
            float bias = rel_table[(di * 5 + dj) * 4 + head];
            sc[kt] = dot * 0.25f + bias;   // SCALE = 16^-0.5 = 0.25
            mx = fmaxf(mx, sc[kt]);
        }
        float ssum = 0.f;
        for (int kt = 0; kt < 9; ++kt) { sc[kt] = expf(sc[kt] - mx); ssum += sc[kt]; }
        float inv = 1.f / ssum;
        float ov[16];
        #pragma unroll
        for (int d = 0; d < 16; ++d) ov[d] = 0.f;
        for (int kt = 0; kt < 9; ++kt) {
            float a = sc[kt] * inv;
            #pragma unroll
            for (int d = 0; d < 16; ++d)
                ov[d] += a * qkv_s[win * 9 + kt][128 + d * 4 + head];
        }
        // output channel = head*16 + d
        size_t base = ((((size_t)b * 64) + u * 8 + win) * 9 + qtok) * 64 + head * 16;
        #pragma unroll
        for (int m = 0; m < 4; ++m)
            *(float4*)&o1[base + 4 * m] =
                make_float4(ov[4 * m], ov[4 * m + 1], ov[4 * m + 2], ov[4 * m + 3]);
    }
}

// ---------------------------------------------------------------------------
// KB: 3x3 conv (pad 1) on each 3x3 window + conv bias + proj GEMM + proj bias.
// One block per (b, u) = 8 windows. o_proj layout: [B*576][128], row = b*576+l.
// ---------------------------------------------------------------------------
__global__ __launch_bounds__(512) void kb_kernel(
    const float* __restrict__ o1, const float* __restrict__ conv_w,
    const float* __restrict__ conv_b, const float* __restrict__ proj_w,
    const float* __restrict__ proj_b, float* __restrict__ o_proj)
{
    const int u = blockIdx.x, b = blockIdx.y, tid = threadIdx.x;
    __shared__ __align__(16) float in_t[72][64];    // attn out [p][c]
    __shared__ __align__(16) float co[72][132];     // conv out [p][oc]
    __shared__ __align__(16) float pwT[128][132];   // proj_w transposed [c][oc2]
    __shared__ __align__(16) float cb_s[128];
    __shared__ __align__(16) float pb_s[128];

    const float* src = o1 + (((size_t)b * 64 + u * 8) * 9) * 64;
    for (int idx = tid; idx < 72 * 64; idx += 512)
        ((float*)in_t)[idx] = src[idx];
    for (int idx = tid; idx < 16384; idx += 512) {
        int oc = idx >> 7, c = idx & 127;
        pwT[c][oc] = proj_w[idx];
    }
    if (tid < 128) { cb_s[tid] = conv_b[tid]; pb_s[tid] = proj_b[tid]; }
    __syncthreads();

    // conv: thread = (oc, group of 18 positions); weights streamed from L2.
    {
        const int ocl = tid & 127;
        const int pg = tid >> 7;                    // 0..3 -> windows pg*2, pg*2+1
        float acc[18];
        #pragma unroll
        for (int i = 0; i < 18; ++i) acc[i] = cb_s[ocl];
        const float* wb = conv_w + (size_t)ocl * 576;  // [64 ic][3][3]
        for (int ic = 0; ic < 64; ic += 4) {
            float wr[36];                           // wr[k*9+tap] = w[oc][ic+k][tap]
            #pragma unroll
            for (int m = 0; m < 9; ++m)
                *(float4*)&wr[4 * m] = *(const float4*)(wb + ic * 9 + 4 * m);
            #pragma unroll
            for (int sw = 0; sw < 2; ++sw) {
                const int win = pg * 2 + sw;
                #pragma unroll
                for (int st = 0; st < 9; ++st) {    // source token
                    float4 xin = *(const float4*)&in_t[win * 9 + st][ic];
                    const int si = st / 3, sj = st % 3;
                    #pragma unroll
                    for (int ii = 0; ii < 3; ++ii) {
                        if (ii - si < -1 || ii - si > 1) continue;
                        #pragma unroll
                        for (int jj = 0; jj < 3; ++jj) {
                            if (jj - sj < -1 || jj - sj > 1) continue;
                            const int tap = (si - ii + 1) * 3 + (sj - jj + 1);
                            const int pl = sw * 9 + ii * 3 + jj;
                            acc[pl] += xin.x * wr[tap] + xin.y * wr[9 + tap] +
                                       xin.z * wr[18 + tap] + xin.w * wr[27 + tap];
                        }
                    }
                }
            }
        }
        #pragma unroll
        for (int i = 0; i < 18; ++i) co[pg * 18 + i][ocl] = acc[i];
    }
    __syncthreads();

    // proj: 4p x 4j register tiles. 18*32 = 576 tiles.
    for (int o = tid; o < 576; o += 512) {
        const int p0 = (o >> 5) * 4;
        const int j0 = (o & 31) * 4;
        float4 a0 = *(const float4*)&pb_s[j0];
        float4 a1 = a0, a2 = a0, a3 = a0;
        for (int c = 0; c < 128; c += 4) {
            float4 x0 = *(const float4*)&co[p0 + 0][c];
            float4 x1 = *(const float4*)&co[p0 + 1][c];
            float4 x2 = *(const float4*)&co[p0 + 2][c];
            float4 x3 = *(const float4*)&co[p0 + 3][c];
            float4 w0 = *(const float4*)&pwT[c + 0][j0];
            float4 w1 = *(const float4*)&pwT[c + 1][j0];
            float4 w2 = *(const float4*)&pwT[c + 2][j0];
            float4 w3 = *(const float4*)&pwT[c + 3][j0];
            DOT4(a0, x0, w0, w1, w2, w3)
            DOT4(a1, x1, w0, w1, w2, w3)
            DOT4(a2, x2, w0, w1, w2, w3)
            DOT4(a3, x3, w0, w1, w2, w3)
        }
        #pragma unroll
        for (int k = 0; k < 4; ++k) {
            const int p = p0 + k;
            const int win = p / 9, tok = p % 9;
            const int l = (u * 3 + tok / 3) * 24 + win * 3 + (tok % 3);
            float4 vv = (k == 0) ? a0 : ((k == 1) ? a1 : ((k == 2) ? a2 : a3));
            *(float4*)&o_proj[((size_t)b * 576 + l) * 128 + j0] = vv;
        }
    }
}

// ---------------------------------------------------------------------------
// KC: LN2 + fc1 + exact GELU + fc2 + residual + transpose to (B,128,576).
// One block per 32 consecutive rows of o_proj. 256 threads (4x4 reg tiles:
// bigger tiles = 1.0 B/FLOP LDS traffic; 512 thr would be 1.5 and LDS-bound).
// ---------------------------------------------------------------------------
__device__ __forceinline__ float gelu_exact(float v) {
    return 0.5f * v * (1.f + erff(v * 0.70710678118654752f));
}

__global__ __launch_bounds__(256) void kc_kernel(
    const float* __restrict__ o_proj,
    const float* __restrict__ fc1_w, const float* __restrict__ fc1_b,
    const float* __restrict__ fc2_w, const float* __restrict__ fc2_b,
    const float* __restrict__ n2g, const float* __restrict__ n2b,
    float* __restrict__ out)
{
    const int tid = threadIdx.x;
    const size_t bl0 = (size_t)blockIdx.x * 32;
    __shared__ __align__(16) float orig[32][132];
    __shared__ __align__(16) float yb[32][132];
    __shared__ __align__(16) float hb[32][260];
    __shared__ __align__(16) float outT[128][33];
    __shared__ __align__(16) float wbuf[17408];     // 69632 B: fwT / fw2T union
    __shared__ float ms[32], rs[32];

    const float* srcp = o_proj + bl0 * 128;
    for (int idx = tid; idx < 4096; idx += 256)
        orig[idx >> 7][idx & 127] = srcp[idx];
    __syncthreads();
    // LN stats: 8 lanes per row, shfl-xor tree (groups within a wave)
    {
        const int r = tid >> 3, q = tid & 7;
        float s = 0.f, sq = 0.f;
        #pragma unroll
        for (int c = 0; c < 16; c += 4) {
            float4 v = *(const float4*)&orig[r][q * 16 + c];
            s  += v.x + v.y + v.z + v.w;
            sq += v.x*v.x + v.y*v.y + v.z*v.z + v.w*v.w;
        }
        s += __shfl_xor(s, 1); sq += __shfl_xor(sq, 1);
        s += __shfl_xor(s, 2); sq += __shfl_xor(sq, 2);
        s += __shfl_xor(s, 4); sq += __shfl_xor(sq, 4);
        if (q == 0) {
            float m = s * (1.f / 128.f);
            float var = sq * (1.f / 128.f) - m * m;
            ms[r] = m; rs[r] = rsqrtf(var + 1e-5f);
        }
    }
    __syncthreads();
    for (int idx = tid; idx < 4096; idx += 256) {
        int r = idx >> 7, c = idx & 127;
        yb[r][c] = (orig[r][c] - ms[r]) * rs[r] * n2g[c] + n2b[c];
    }

    // fc1 + gelu, 2 chunks of 128 hidden
    float (*fwT)[132] = (float(*)[132])wbuf;        // [c 128][jl 128]
    for (int ch = 0; ch < 2; ++ch) {
        __syncthreads();
        for (int idx = tid; idx < 16384; idx += 256) {
            int jl = idx >> 7, c = idx & 127;
            fwT[c][jl] = fc1_w[(size_t)ch * 16384 + idx];
        }
        __syncthreads();
        {
            const int r0 = (tid >> 5) * 4;
            const int j0 = (tid & 31) * 4;
            float4 a0 = *(const float4*)&fc1_b[ch * 128 + j0];
            float4 a1 = a0, a2 = a0, a3 = a0;
            for (int c = 0; c < 128; c += 4) {
                float4 x0 = *(const float4*)&yb[r0 + 0][c];
                float4 x1 = *(const float4*)&yb[r0 + 1][c];
                float4 x2 = *(const float4*)&yb[r0 + 2][c];
                float4 x3 = *(const float4*)&yb[r0 + 3][c];
                float4 w0 = *(const float4*)&fwT[c + 0][j0];
                float4 w1 = *(const float4*)&fwT[c + 1][j0];
                float4 w2 = *(const float4*)&fwT[c + 2][j0];
                float4 w3 = *(const float4*)&fwT[c + 3][j0];
                DOT4(a0, x0, w0, w1, w2, w3)
                DOT4(a1, x1, w0, w1, w2, w3)
                DOT4(a2, x2, w0, w1, w2, w3)
                DOT4(a3, x3, w0, w1, w2, w3)
            }
            a0.x = gelu_exact(a0.x); a0.y = gelu_exact(a0.y); a0.z = gelu_exact(a0.z); a0.w = gelu_exact(a0.w);
            a1.x = gelu_exact(a1.x); a1.y = gelu_exact(a1.y); a1.z = gelu_exact(a1.z); a1.w = gelu_exact(a1.w);
            a2.x = gelu_exact(a2.x); a2.y = gelu_exact(a2.y); a2.z = gelu_exact(a2.z); a2.w = gelu_exact(a2.w);
            a3.x = gelu_exact(a3.x); a3.y = gelu_exact(a3.y); a3.z = gelu_exact(a3.z); a3.w = gelu_exact(a3.w);
            *(float4*)&hb[r0 + 0][ch * 128 + j0] = a0;
            *(float4*)&hb[r0 + 1][ch * 128 + j0] = a1;
            *(float4*)&hb[r0 + 2][ch * 128 + j0] = a2;
            *(float4*)&hb[r0 + 3][ch * 128 + j0] = a3;
        }
    }

    // fc2 + bias + residual, 2 chunks of 64 out-channels
    float (*fw2T)[68] = (float(*)[68])wbuf;         // [j 256][ol 64]
    for (int ch = 0; ch < 2; ++ch) {
        __syncthreads();
        for (int idx = tid; idx < 16384; idx += 256) {
            int ol = idx >> 8, jj = idx & 255;
            fw2T[jj][ol] = fc2_w[(size_t)ch * 16384 + idx];
        }
        __syncthreads();
        {
            const int r0 = (tid >> 4) * 2;
            const int c0 = (tid & 15) * 4;
            const int cg = ch * 64 + c0;
            float4 a0 = *(const float4*)&fc2_b[cg];
            float4 a1 = a0;
            float4 og0 = *(const float4*)&orig[r0 + 0][cg];
            float4 og1 = *(const float4*)&orig[r0 + 1][cg];
            a0.x += og0.x; a0.y += og0.y; a0.z += og0.z; a0.w += og0.w;
            a1.x += og1.x; a1.y += og1.y; a1.z += og1.z; a1.w += og1.w;
            for (int j = 0; j < 256; j += 4) {
                float4 h0 = *(const float4*)&hb[r0 + 0][j];
                float4 h1 = *(const float4*)&hb[r0 + 1][j];
                float4 w0 = *(const float4*)&fw2T[j + 0][c0];
                float4 w1 = *(const float4*)&fw2T[j + 1][c0];
                float4 w2 = *(const float4*)&fw2T[j + 2][c0];
                float4 w3 = *(const float4*)&fw2T[j + 3][c0];
                DOT4(a0, h0, w0, w1, w2, w3)
                DOT4(a1, h1, w0, w1, w2, w3)
            }
            outT[cg + 0][r0] = a0.x; outT[cg + 1][r0] = a0.y;
            outT[cg + 2][r0] = a0.z; outT[cg + 3][r0] = a0.w;
            outT[cg + 0][r0 + 1] = a1.x; outT[cg + 1][r0 + 1] = a1.y;
            outT[cg + 2][r0 + 1] = a1.z; outT[cg + 3][r0 + 1] = a1.w;
        }
    }
    __syncthreads();

    const int bo = (int)(bl0 / 576);
    const int l0 = (int)(bl0 % 576);
    for (int idx = tid; idx < 4096; idx += 256) {
        int c = idx >> 5, r = idx & 31;
        out[((size_t)bo * 128 + c) * 576 + l0 + r] = outT[c][r];
    }
}

// ---------------------------------------------------------------------------
extern "C" void kernel_launch(void* const* d_in, const int* in_sizes, int n_in,
                              void* d_out, int out_size, void* d_ws, size_t ws_size,
                              hipStream_t stream) {
    (void)in_sizes; (void)n_in; (void)out_size; (void)ws_size;
    const float* x      = (const float*)d_in[0];
    const float* qkv_w  = (const float*)d_in[1];
    const float* qkv_b  = (const float*)d_in[2];
    const float* rel    = (const float*)d_in[3];
    const float* proj_w = (const float*)d_in[4];
    const float* proj_b = (const float*)d_in[5];
    const float* fc1_w  = (const float*)d_in[6];
    const float* fc1_b  = (const float*)d_in[7];
    const float* fc2_w  = (const float*)d_in[8];
    const float* fc2_b  = (const float*)d_in[9];
    const float* n1g    = (const float*)d_in[10];
    const float* n1b    = (const float*)d_in[11];
    const float* n2g    = (const float*)d_in[12];
    const float* n2b    = (const float*)d_in[13];
    const float* conv_w = (const float*)d_in[14];
    const float* conv_b = (const float*)d_in[15];
    float* out = (float*)d_out;

    float* o1     = (float*)d_ws;                        // 512*64*9*64 = 18,874,368 f
    float* o_proj = o1 + (size_t)512 * 64 * 9 * 64;      // 512*576*128 = 37,748,736 f

    ka_kernel<<<dim3(8, 512), 512, 0, stream>>>(x, qkv_w, qkv_b, rel, n1g, n1b, o1);
    kb_kernel<<<dim3(8, 512), 512, 0, stream>>>(o1, conv_w, conv_b, proj_w, proj_b, o_proj);
    kc_kernel<<<9216, 256, 0, stream>>>(o_proj, fc1_w, fc1_b, fc2_w, fc2_b, n2g, n2b, out);
}

// Round 11
// 1806.064 us; speedup vs baseline: 1.4938x; 1.4938x over previous
//
#include <hip/hip_runtime.h>
#include <math.h>

#define NL 576   // H*W = 24*24
#define NCH 64   // DIM

typedef __attribute__((ext_vector_type(8))) short bf16x8;
typedef __attribute__((ext_vector_type(4))) float f32x4;

__device__ __forceinline__ unsigned short f2bf(float f) {
    unsigned u = __float_as_uint(f);
    return (unsigned short)((u + 0x7FFFu + ((u >> 16) & 1u)) >> 16);
}

#define DOT4(acc, xv, w0, w1, w2, w3)                               \
    acc.x += xv.x*w0.x + xv.y*w1.x + xv.z*w2.x + xv.w*w3.x;         \
    acc.y += xv.x*w0.y + xv.y*w1.y + xv.z*w2.y + xv.w*w3.y;         \
    acc.z += xv.x*w0.z + xv.y*w1.z + xv.z*w2.z + xv.w*w3.z;         \
    acc.w += xv.x*w0.w + xv.y*w1.w + xv.z*w2.w + xv.w*w3.w;

// ---------------------------------------------------------------------------
// kcvt: fp32 -> bf16 weight repack for the MLP, into the exact LDS tile
// layout kc2 stages: [2 chunks][128 rows][136 cols] (8-col zero pad).
// w1 chunk hc row j: fc1_w[hc*128+j][0..127]; w2 chunk hc row c: fc2_w[c][hc*128..+127]
// ---------------------------------------------------------------------------
__global__ __launch_bounds__(256) void kcvt_kernel(
    const float* __restrict__ fc1_w, const float* __restrict__ fc2_w,
    unsigned short* __restrict__ w1, unsigned short* __restrict__ w2)
{
    int i = blockIdx.x * 256 + threadIdx.x;   // grid 136*256 = 34816 exactly
    if (i < 34816) {
        int hc = i / 17408, rr = i % 17408, jr = rr / 136, kk = rr % 136;
        float v1 = (kk < 128) ? fc1_w[(size_t)(hc * 128 + jr) * 128 + kk] : 0.f;
        w1[i] = f2bf(v1);
        float v2 = (kk < 128) ? fc2_w[(size_t)jr * 256 + hc * 128 + kk] : 0.f;
        w2[i] = f2bf(v2);
    }
}

// ---------------------------------------------------------------------------
// KA: LN1 + QKV projection + windowed attention.  (unchanged, fp32)
// ---------------------------------------------------------------------------
__global__ __launch_bounds__(512) void ka_kernel(
    const float* __restrict__ x, const float* __restrict__ qkv_w,
    const float* __restrict__ qkv_b, const float* __restrict__ rel_table,
    const float* __restrict__ n1g, const float* __restrict__ n1b,
    float* __restrict__ o1)
{
    const int u = blockIdx.x;
    const int b = blockIdx.y;
    const int tid = threadIdx.x;

    __shared__ __align__(16) float xt[72][68];
    __shared__ __align__(16) float qwT[64][200];
    __shared__ __align__(16) float qkv_s[72][200];
    __shared__ __align__(16) float qb_s[192];
    __shared__ float mean_s[72], rstd_s[72];

    const float* xb = x + (size_t)b * NCH * NL;

    for (int idx = tid; idx < 64 * 72; idx += 512) {
        int c = idx / 72, r = idx % 72;
        int hi = r / 24, wc = r % 24;
        int p = (wc / 3) * 9 + hi * 3 + (wc % 3);
        xt[p][c] = xb[c * NL + (u * 3 + hi) * 24 + wc];
    }
    for (int idx = tid; idx < 12288; idx += 512) {
        int j = idx >> 6, c = idx & 63;
        qwT[c][j] = qkv_w[idx];
    }
    if (tid < 192) qb_s[tid] = qkv_b[tid];
    __syncthreads();

    if (tid < 288) {
        const int p = tid >> 2, q = tid & 3;
        float s = 0.f, sq = 0.f;
        #pragma unroll
        for (int c = 0; c < 16; c += 4) {
            float4 v = *(const float4*)&xt[p][q * 16 + c];
            s  += v.x + v.y + v.z + v.w;
            sq += v.x*v.x + v.y*v.y + v.z*v.z + v.w*v.w;
        }
        s += __shfl_xor(s, 1); sq += __shfl_xor(sq, 1);
        s += __shfl_xor(s, 2); sq += __shfl_xor(sq, 2);
        if (q == 0) {
            float m = s * 0.015625f;
            float var = sq * 0.015625f - m * m;
            mean_s[p] = m;
            rstd_s[p] = rsqrtf(var + 1e-5f);
        }
    }
    __syncthreads();
    for (int idx = tid; idx < 72 * 64; idx += 512) {
        int p = idx >> 6, c = idx & 63;
        xt[p][c] = (xt[p][c] - mean_s[p]) * rstd_s[p] * n1g[c] + n1b[c];
    }
    __syncthreads();

    for (int o = tid; o < 864; o += 512) {
        const int p0 = (o / 48) * 4;
        const int j0 = (o % 48) * 4;
        float4 a0 = *(const float4*)&qb_s[j0];
        float4 a1 = a0, a2 = a0, a3 = a0;
        for (int c = 0; c < 64; c += 4) {
            float4 x0 = *(const float4*)&xt[p0 + 0][c];
            float4 x1 = *(const float4*)&xt[p0 + 1][c];
            float4 x2 = *(const float4*)&xt[p0 + 2][c];
            float4 x3 = *(const float4*)&xt[p0 + 3][c];
            float4 w0 = *(const float4*)&qwT[c + 0][j0];
            float4 w1 = *(const float4*)&qwT[c + 1][j0];
            float4 w2 = *(const float4*)&qwT[c + 2][j0];
            float4 w3 = *(const float4*)&qwT[c + 3][j0];
            DOT4(a0, x0, w0, w1, w2, w3)
            DOT4(a1, x1, w0, w1, w2, w3)
            DOT4(a2, x2, w0, w1, w2, w3)
            DOT4(a3, x3, w0, w1, w2, w3)
        }
        *(float4*)&qkv_s[p0 + 0][j0] = a0;
        *(float4*)&qkv_s[p0 + 1][j0] = a1;
        *(float4*)&qkv_s[p0 + 2][j0] = a2;
        *(float4*)&qkv_s[p0 + 3][j0] = a3;
    }
    __syncthreads();

    if (tid < 288) {
        const int win = tid / 36;
        const int rr = tid % 36;
        const int head = rr / 9, qtok = rr % 9;
        const int qi = qtok / 3, qj = qtok % 3;
        float sc[9];
        float mx = -1e30f;
        for (int kt = 0; kt < 9; ++kt) {
            float dot = 0.f;
            for (int d = 0; d < 16; ++d)
                dot += qkv_s[win * 9 + qtok][d * 4 + head] *
                       qkv_s[win * 9 + kt][64 + d * 4 + head];
            int di = qi - kt / 3 + 2, dj = qj - kt % 3 + 2;
            float bias = rel_table[(di * 5 + dj) * 4 + head];
            sc[kt] = dot * 0.25f + bias;
            mx = fmaxf(mx, sc[kt]);
        }
        float ssum = 0.f;
        for (int kt = 0; kt < 9; ++kt) { sc[kt] = expf(sc[kt] - mx); ssum += sc[kt]; }
        float inv = 1.f / ssum;
        float ov[16];
        #pragma unroll
        for (int d = 0; d < 16; ++d) ov[d] = 0.f;
        for (int kt = 0; kt < 9; ++kt) {
            float a = sc[kt] * inv;
            #pragma unroll
            for (int d = 0; d < 16; ++d)
                ov[d] += a * qkv_s[win * 9 + kt][128 + d * 4 + head];
        }
        size_t base = ((((size_t)b * 64) + u * 8 + win) * 9 + qtok) * 64 + head * 16;
        #pragma unroll
        for (int m = 0; m < 4; ++m)
            *(float4*)&o1[base + 4 * m] =
                make_float4(ov[4 * m], ov[4 * m + 1], ov[4 * m + 2], ov[4 * m + 3]);
    }
}

// ---------------------------------------------------------------------------
// KB: 3x3 conv on 3x3 windows + proj GEMM.  (unchanged, fp32)
// ---------------------------------------------------------------------------
__global__ __launch_bounds__(512) void kb_kernel(
    const float* __restrict__ o1, const float* __restrict__ conv_w,
    const float* __restrict__ conv_b, const float* __restrict__ proj_w,
    const float* __restrict__ proj_b, float* __restrict__ o_proj)
{
    const int u = blockIdx.x, b = blockIdx.y, tid = threadIdx.x;
    __shared__ __align__(16) float in_t[72][64];
    __shared__ __align__(16) float co[72][132];
    __shared__ __align__(16) float pwT[128][132];
    __shared__ __align__(16) float cb_s[128];
    __shared__ __align__(16) float pb_s[128];

    const float* src = o1 + (((size_t)b * 64 + u * 8) * 9) * 64;
    for (int idx = tid; idx < 72 * 64; idx += 512)
        ((float*)in_t)[idx] = src[idx];
    for (int idx = tid; idx < 16384; idx += 512) {
        int oc = idx >> 7, c = idx & 127;
        pwT[c][oc] = proj_w[idx];
    }
    if (tid < 128) { cb_s[tid] = conv_b[tid]; pb_s[tid] = proj_b[tid]; }
    __syncthreads();

    {
        const int ocl = tid & 127;
        const int pg = tid >> 7;
        float acc[18];
        #pragma unroll
        for (int i = 0; i < 18; ++i) acc[i] = cb_s[ocl];
        const float* wb = conv_w + (size_t)ocl * 576;
        for (int ic = 0; ic < 64; ic += 4) {
            float wr[36];
            #pragma unroll
            for (int m = 0; m < 9; ++m)
                *(float4*)&wr[4 * m] = *(const float4*)(wb + ic * 9 + 4 * m);
            #pragma unroll
            for (int sw = 0; sw < 2; ++sw) {
                const int win = pg * 2 + sw;
                #pragma unroll
                for (int st = 0; st < 9; ++st) {
                    float4 xin = *(const float4*)&in_t[win * 9 + st][ic];
                    const int si = st / 3, sj = st % 3;
                    #pragma unroll
                    for (int ii = 0; ii < 3; ++ii) {
                        if (ii - si < -1 || ii - si > 1) continue;
                        #pragma unroll
                        for (int jj = 0; jj < 3; ++jj) {
                            if (jj - sj < -1 || jj - sj > 1) continue;
                            const int tap = (si - ii + 1) * 3 + (sj - jj + 1);
                            const int pl = sw * 9 + ii * 3 + jj;
                            acc[pl] += xin.x * wr[tap] + xin.y * wr[9 + tap] +
                                       xin.z * wr[18 + tap] + xin.w * wr[27 + tap];
                        }
                    }
                }
            }
        }
        #pragma unroll
        for (int i = 0; i < 18; ++i) co[pg * 18 + i][ocl] = acc[i];
    }
    __syncthreads();

    for (int o = tid; o < 576; o += 512) {
        const int p0 = (o >> 5) * 4;
        const int j0 = (o & 31) * 4;
        float4 a0 = *(const float4*)&pb_s[j0];
        float4 a1 = a0, a2 = a0, a3 = a0;
        for (int c = 0; c < 128; c += 4) {
            float4 x0 = *(const float4*)&co[p0 + 0][c];
            float4 x1 = *(const float4*)&co[p0 + 1][c];
            float4 x2 = *(const float4*)&co[p0 + 2][c];
            float4 x3 = *(const float4*)&co[p0 + 3][c];
            float4 w0 = *(const float4*)&pwT[c + 0][j0];
            float4 w1 = *(const float4*)&pwT[c + 1][j0];
            float4 w2 = *(const float4*)&pwT[c + 2][j0];
            float4 w3 = *(const float4*)&pwT[c + 3][j0];
            DOT4(a0, x0, w0, w1, w2, w3)
            DOT4(a1, x1, w0, w1, w2, w3)
            DOT4(a2, x2, w0, w1, w2, w3)
            DOT4(a3, x3, w0, w1, w2, w3)
        }
        #pragma unroll
        for (int k = 0; k < 4; ++k) {
            const int p = p0 + k;
            const int win = p / 9, tok = p % 9;
            const int l = (u * 3 + tok / 3) * 24 + win * 3 + (tok % 3);
            float4 vv = (k == 0) ? a0 : ((k == 1) ? a1 : ((k == 2) ? a2 : a3));
            *(float4*)&o_proj[((size_t)b * 576 + l) * 128 + j0] = vv;
        }
    }
}

// ---------------------------------------------------------------------------
// kc2: LN2 + fc1 + GELU + fc2 + residual + NCHW transpose, bf16 MFMA.
// 64 rows/block (64|576: no batch straddle), 4 waves x one 16-row M-tile.
// Two hidden-chunks of 128; weights staged per chunk from kcvt's bf16 layout.
// MFMA 16x16x32: A lane=m+16*kb holds k=kb*8+j; B symmetric; C/D: col=lane&15,
// row=(lane>>4)*4+reg (m89-verified).
// ---------------------------------------------------------------------------
__global__ __launch_bounds__(256) void kc2_kernel(
    const float* __restrict__ o_proj,
    const unsigned short* __restrict__ w1bf, const unsigned short* __restrict__ w2bf,
    const float* __restrict__ fc1_b, const float* __restrict__ fc2_b,
    const float* __restrict__ n2g, const float* __restrict__ n2b,
    float* __restrict__ out)
{
    const int tid = threadIdx.x;
    const int blk = blockIdx.x;
    __shared__ unsigned short yb[64][136];    // LN'd rows, bf16
    __shared__ unsigned short hb[64][136];    // hidden chunk, bf16 (wave-private rows)
    __shared__ unsigned short w1s[128][136];  // fc1 weight chunk
    __shared__ unsigned short w2s[128][136];  // fc2 weight chunk
    __shared__ float ng[128], nb[128];

    if (tid < 128) { ng[tid] = n2g[tid]; nb[tid] = n2b[tid]; }

    // ---- LN2: 4 lanes per row (rows of this wave only) ----
    const int r_loc = tid >> 2, q = tid & 3;
    const size_t row0 = (size_t)blk * 64 + r_loc;
    float xv[32];
    {
        const float* srcp = o_proj + row0 * 128 + q * 32;
        #pragma unroll
        for (int i = 0; i < 8; ++i) {
            float4 v = *(const float4*)(srcp + i * 4);
            xv[i*4] = v.x; xv[i*4+1] = v.y; xv[i*4+2] = v.z; xv[i*4+3] = v.w;
        }
    }
    float s = 0.f, sq = 0.f;
    #pragma unroll
    for (int i = 0; i < 32; ++i) { s += xv[i]; sq += xv[i]*xv[i]; }
    s += __shfl_xor(s, 1); sq += __shfl_xor(sq, 1);
    s += __shfl_xor(s, 2); sq += __shfl_xor(sq, 2);
    const float mean = s * (1.f / 128.f);
    const float rstd = rsqrtf(sq * (1.f / 128.f) - mean * mean + 1e-5f);
    __syncthreads();   // ng/nb ready
    #pragma unroll
    for (int i = 0; i < 32; i += 8) {
        uint4 pk;
        unsigned v0, v1;
        v0 = f2bf((xv[i+0]-mean)*rstd*ng[q*32+i+0] + nb[q*32+i+0]);
        v1 = f2bf((xv[i+1]-mean)*rstd*ng[q*32+i+1] + nb[q*32+i+1]);
        pk.x = v0 | (v1 << 16);
        v0 = f2bf((xv[i+2]-mean)*rstd*ng[q*32+i+2] + nb[q*32+i+2]);
        v1 = f2bf((xv[i+3]-mean)*rstd*ng[q*32+i+3] + nb[q*32+i+3]);
        pk.y = v0 | (v1 << 16);
        v0 = f2bf((xv[i+4]-mean)*rstd*ng[q*32+i+4] + nb[q*32+i+4]);
        v1 = f2bf((xv[i+5]-mean)*rstd*ng[q*32+i+5] + nb[q*32+i+5]);
        pk.z = v0 | (v1 << 16);
        v0 = f2bf((xv[i+6]-mean)*rstd*ng[q*32+i+6] + nb[q*32+i+6]);
        v1 = f2bf((xv[i+7]-mean)*rstd*ng[q*32+i+7] + nb[q*32+i+7]);
        pk.w = v0 | (v1 << 16);
        *(uint4*)&yb[r_loc][q * 32 + i] = pk;
    }

    // ---- MFMA phases ----
    const int wid = tid >> 6, lane = tid & 63, fr = lane & 15, kb = lane >> 4;
    f32x4 oacc[8];
    #pragma unroll
    for (int j = 0; j < 8; ++j) oacc[j] = (f32x4){0.f, 0.f, 0.f, 0.f};

    for (int hc = 0; hc < 2; ++hc) {
        __syncthreads();   // previous chunk's weight readers done
        {
            const uint4* s1 = (const uint4*)(w1bf + hc * 17408);
            const uint4* s2 = (const uint4*)(w2bf + hc * 17408);
            uint4* d1 = (uint4*)&w1s[0][0];
            uint4* d2 = (uint4*)&w2s[0][0];
            for (int i = tid; i < 2176; i += 256) { d1[i] = s1[i]; d2[i] = s2[i]; }
        }
        __syncthreads();   // weights staged

        // fc1: this wave's 16 rows x 128 hidden cols of this chunk
        bf16x8 a1[4];
        #pragma unroll
        for (int ss = 0; ss < 4; ++ss)
            a1[ss] = *(const bf16x8*)&yb[wid * 16 + fr][ss * 32 + kb * 8];
        #pragma unroll
        for (int jt = 0; jt < 8; ++jt) {
            f32x4 acc = (f32x4){0.f, 0.f, 0.f, 0.f};
            #pragma unroll
            for (int ss = 0; ss < 4; ++ss) {
                bf16x8 bfr = *(const bf16x8*)&w1s[jt * 16 + fr][ss * 32 + kb * 8];
                acc = __builtin_amdgcn_mfma_f32_16x16x32_bf16(a1[ss], bfr, acc, 0, 0, 0);
            }
            const float bias = fc1_b[hc * 128 + jt * 16 + fr];
            #pragma unroll
            for (int rg = 0; rg < 4; ++rg) {
                float v = acc[rg] + bias;
                v = 0.5f * v * (1.f + erff(v * 0.70710678118654752f));
                hb[wid * 16 + kb * 4 + rg][jt * 16 + fr] = f2bf(v);
            }
        }
        __syncthreads();   // conservative: hb visible (wave-private, but cheap)

        // fc2: accumulate over this chunk's 128 hidden
        bf16x8 a2[4];
        #pragma unroll
        for (int ss = 0; ss < 4; ++ss)
            a2[ss] = *(const bf16x8*)&hb[wid * 16 + fr][ss * 32 + kb * 8];
        #pragma unroll
        for (int jt = 0; jt < 8; ++jt) {
            #pragma unroll
            for (int ss = 0; ss < 4; ++ss) {
                bf16x8 bfr = *(const bf16x8*)&w2s[jt * 16 + fr][ss * 32 + kb * 8];
                oacc[jt] = __builtin_amdgcn_mfma_f32_16x16x32_bf16(a2[ss], bfr, oacc[jt], 0, 0, 0);
            }
        }
    }

    // ---- epilogue: bias + residual + transposed store ----
    const int bo = blk / 9;
    const int l0 = (blk % 9) * 64;
    #pragma unroll
    for (int jt = 0; jt < 8; ++jt) {
        const int c2 = jt * 16 + fr;
        const float bias = fc2_b[c2];
        #pragma unroll
        for (int rg = 0; rg < 4; ++rg) {
            const int mm = wid * 16 + kb * 4 + rg;
            const size_t rowg = (size_t)blk * 64 + mm;
            const float resid = o_proj[rowg * 128 + c2];
            out[((size_t)bo * 128 + c2) * 576 + l0 + mm] = oacc[jt][rg] + bias + resid;
        }
    }
}

// ---------------------------------------------------------------------------
extern "C" void kernel_launch(void* const* d_in, const int* in_sizes, int n_in,
                              void* d_out, int out_size, void* d_ws, size_t ws_size,
                              hipStream_t stream) {
    (void)in_sizes; (void)n_in; (void)out_size; (void)ws_size;
    const float* x      = (const float*)d_in[0];
    const float* qkv_w  = (const float*)d_in[1];
    const float* qkv_b  = (const float*)d_in[2];
    const float* rel    = (const float*)d_in[3];
    const float* proj_w = (const float*)d_in[4];
    const float* proj_b = (const float*)d_in[5];
    const float* fc1_w  = (const float*)d_in[6];
    const float* fc1_b  = (const float*)d_in[7];
    const float* fc2_w  = (const float*)d_in[8];
    const float* fc2_b  = (const float*)d_in[9];
    const float* n1g    = (const float*)d_in[10];
    const float* n1b    = (const float*)d_in[11];
    const float* n2g    = (const float*)d_in[12];
    const float* n2b    = (const float*)d_in[13];
    const float* conv_w = (const float*)d_in[14];
    const float* conv_b = (const float*)d_in[15];
    float* out = (float*)d_out;

    float* o1     = (float*)d_ws;                        // 18,874,368 f
    float* o_proj = o1 + (size_t)512 * 64 * 9 * 64;      // 37,748,736 f
    // bf16 weight repack area after o_proj: byte offset 226,492,416 (16-aligned)
    unsigned short* w1u = (unsigned short*)d_ws + (size_t)113246208;
    unsigned short* w2u = w1u + 34816;

    kcvt_kernel<<<136, 256, 0, stream>>>(fc1_w, fc2_w, w1u, w2u);
    ka_kernel<<<dim3(8, 512), 512, 0, stream>>>(x, qkv_w, qkv_b, rel, n1g, n1b, o1);
    kb_kernel<<<dim3(8, 512), 512, 0, stream>>>(o1, conv_w, conv_b, proj_w, proj_b, o_proj);
    kc2_kernel<<<4608, 256, 0, stream>>>(o_proj, w1u, w2u, fc1_b, fc2_b, n2g, n2b, out);
}